// Round 1
// baseline (5626.557 us; speedup 1.0000x reference)
//
#include <hip/hip_runtime.h>
#include <cstdint>
#include <cstddef>

typedef __bf16 bf16_t;
typedef __bf16 bf16x8 __attribute__((ext_vector_type(8)));
typedef __bf16 bf16x4 __attribute__((ext_vector_type(4)));
typedef float f32x4 __attribute__((ext_vector_type(4)));

#define N_TIN 336
#define N_TOUT 96
#define N_B   2048
#define N_D   64
#define N_H   512

// ---------------- helpers ----------------
__device__ __forceinline__ void llds16(const void* g, void* l) {
  __builtin_amdgcn_global_load_lds(
      (const __attribute__((address_space(1))) unsigned*)g,
      (__attribute__((address_space(3))) unsigned*)l, 16, 0, 0);
}
__device__ __forceinline__ float sigmf(float x) { return 1.0f / (1.0f + __expf(-x)); }
__device__ __forceinline__ float tanhft(float x) {
  x = fminf(15.0f, fmaxf(-15.0f, x));
  float e = __expf(2.0f * x);
  return (e - 1.0f) / (e + 1.0f);
}
// permuted weight-row order: m = j_hi*256 + (j_mid*4 + ... ) interleaves the 4 gates
// at 16-col fragment granularity so one 64-col wave slice = {i,f,g,o} of 16 h-units.
__device__ __forceinline__ int perm_row(int m) {
  int j_hi = m >> 8;          // which group of 64 h-cols
  int fi   = (m >> 4) & 15;   // fragment index within tile
  int c    = m & 15;
  int gate = fi & 3;          // i,f,g,o
  int j    = j_hi * 64 + (fi >> 2) * 16 + c;
  return gate * N_H + j;      // original row in [4H, *] weight
}

// ---------------- prep kernels (run every call; ws is re-poisoned) ----------------
__global__ void prep_enc_w(const float* __restrict__ Wih, const float* __restrict__ Whh,
                           const float* __restrict__ bih, const float* __restrict__ bhh,
                           bf16_t* __restrict__ Wp, float* __restrict__ bp) {
  int m = blockIdx.x;
  int n = perm_row(m);
  for (int k = threadIdx.x; k < 576; k += 256) {
    float v = (k < 64) ? Wih[n * 64 + k] : Whh[n * 512 + (k - 64)];
    Wp[(size_t)m * 576 + k] = (bf16_t)v;
  }
  if (threadIdx.x == 0) bp[m] = bih[n] + bhh[n];
}

__global__ void prep_dec_w(const float* __restrict__ Wih, const float* __restrict__ Whh,
                           const float* __restrict__ bih, const float* __restrict__ bhh,
                           const float* __restrict__ linW, const float* __restrict__ linb,
                           bf16_t* __restrict__ W0p, bf16_t* __restrict__ Wep,
                           float* __restrict__ b0p, float* __restrict__ bep) {
  int m = blockIdx.x;
  int n = perm_row(m);
  for (int k = threadIdx.x; k < 512; k += 256) {
    float whh = Whh[n * 512 + k];
    W0p[(size_t)m * 512 + k] = (bf16_t)whh;
    float acc = whh;
    #pragma unroll 8
    for (int d = 0; d < 64; ++d) acc += Wih[n * 64 + d] * linW[d * 512 + k];
    Wep[(size_t)m * 512 + k] = (bf16_t)acc;   // W_eff = Whh + Wih @ lin_W
  }
  if (threadIdx.x == 0) {
    float b = bih[n] + bhh[n];
    b0p[m] = b;
    float acc = b;
    for (int d = 0; d < 64; ++d) acc += Wih[n * 64 + d] * linb[d];
    bep[m] = acc;                              // b_eff = b + Wih @ lin_b
  }
}

__global__ void cvt_bf16_v4(const float* __restrict__ src, bf16_t* __restrict__ dst, int n4) {
  int i = blockIdx.x * 256 + threadIdx.x;
  int stride = gridDim.x * 256;
  for (; i < n4; i += stride) {
    float4 v = ((const float4*)src)[i];
    bf16x4 o;
    o[0] = (bf16_t)v.x; o[1] = (bf16_t)v.y; o[2] = (bf16_t)v.z; o[3] = (bf16_t)v.w;
    *(bf16x4*)(dst + (size_t)i * 4) = o;
  }
}

// ---------------- fused LSTM step: gates GEMM + pointwise ----------------
// Tile: 64 batch rows x 256 gate cols (=64 h-units x 4 gates interleaved).
// Grid: (32, 8). 4 waves; wave w owns gate-frags [4w,4w+4) = {i,f,g,o} of 16 h-units.
template<int KTOT, int XK>
__global__ __launch_bounds__(256, 1)
void lstm_step(const bf16_t* __restrict__ x,      // [B][XK] slice (encoder) or null
               const bf16_t* __restrict__ h_in,   // [B][512] bf16
               const bf16_t* __restrict__ Wp,     // [2048][KTOT] permuted bf16
               const float* __restrict__ bp,      // [2048] permuted bias
               float* __restrict__ c,             // [B][512] fp32, in-place
               bf16_t* __restrict__ h_out) {      // [B][512] bf16
  __shared__ __align__(16) char smem[2 * 8192 + 2 * 32768];
  constexpr int NK = KTOT / 64;
  const int tid  = threadIdx.x;
  const int lane = tid & 63;
  const int w    = tid >> 6;
  const int row0 = blockIdx.x * 64;
  const int wg_n = blockIdx.y;
  const int l3 = lane >> 3;
  const int q8 = ((lane & 7) ^ l3) * 8;   // inverse-swizzled source slot (elements)

  auto stage = [&](int kc, int buf) {
    char* Ab = smem + buf * 8192;
    char* Bb = smem + 16384 + buf * 32768;
    #pragma unroll
    for (int ii = 0; ii < 2; ++ii) {               // A: 2 loads/wave, 8 total
      int i  = 2 * w + ii;
      int rl = i * 8 + l3;
      const bf16_t* src;
      if (XK != 0 && kc == 0)
        src = x + (size_t)(row0 + rl) * XK + q8;
      else
        src = h_in + (size_t)(row0 + rl) * N_H + (kc * 64 - XK) + q8;
      llds16(src, Ab + i * 1024);
    }
    #pragma unroll
    for (int jj = 0; jj < 8; ++jj) {               // B: 8 loads/wave, 32 total
      int j  = 8 * w + jj;
      int nl = j * 8 + l3;
      const bf16_t* src = Wp + (size_t)(wg_n * 256 + nl) * KTOT + kc * 64 + q8;
      llds16(src, Bb + j * 1024);
    }
  };

  f32x4 acc[4][4];
  #pragma unroll
  for (int a = 0; a < 4; ++a)
    #pragma unroll
    for (int b = 0; b < 4; ++b) acc[a][b] = (f32x4){0.f, 0.f, 0.f, 0.f};

  const int fr = lane & 15;
  const int g4 = lane >> 4;
  const int px = lane & 7;

  stage(0, 0);
  for (int kc = 0; kc < NK; ++kc) {
    asm volatile("s_waitcnt vmcnt(0)" ::: "memory");  // global_load_lds landed
    __syncthreads();
    if (kc + 1 < NK) stage(kc + 1, (kc + 1) & 1);     // prefetch hides under MFMA
    const char* Ab = smem + (kc & 1) * 8192;
    const char* Bb = smem + 16384 + (kc & 1) * 32768;
    #pragma unroll
    for (int kk = 0; kk < 2; ++kk) {
      bf16x8 av[4], bv[4];
      int p = (kk * 4 + g4) ^ px;                      // XOR-8 bank swizzle
      #pragma unroll
      for (int ri = 0; ri < 4; ++ri)
        av[ri] = *(const bf16x8*)(Ab + (16 * ri + fr) * 128 + p * 16);
      #pragma unroll
      for (int ci = 0; ci < 4; ++ci)
        bv[ci] = *(const bf16x8*)(Bb + ((4 * w + ci) * 16 + fr) * 128 + p * 16);
      #pragma unroll
      for (int ri = 0; ri < 4; ++ri)
        #pragma unroll
        for (int ci = 0; ci < 4; ++ci)
          acc[ri][ci] = __builtin_amdgcn_mfma_f32_16x16x32_bf16(av[ri], bv[ci], acc[ri][ci], 0, 0, 0);
    }
  }

  // pointwise: all 4 gates for (row, j) live in this lane's acc[.][0..3]
  const int jg = wg_n * 64 + w * 16 + fr;
  const int mb = wg_n * 256 + (4 * w) * 16 + fr;
  const float bI = bp[mb], bF = bp[mb + 16], bG = bp[mb + 32], bO = bp[mb + 48];
  #pragma unroll
  for (int ri = 0; ri < 4; ++ri) {
    #pragma unroll
    for (int r = 0; r < 4; ++r) {
      int rowl = 16 * ri + g4 * 4 + r;
      size_t idx = (size_t)(row0 + rowl) * N_H + jg;
      float iv = sigmf(acc[ri][0][r] + bI);
      float fv = sigmf(acc[ri][1][r] + bF);
      float gv = tanhft(acc[ri][2][r] + bG);
      float ov = sigmf(acc[ri][3][r] + bO);
      float cn = fv * c[idx] + iv * gv;
      c[idx] = cn;
      h_out[idx] = (bf16_t)(ov * tanhft(cn));
    }
  }
}

// ---------------- decoder output projection: y = h @ lin_W.T + lin_b ----------------
__global__ __launch_bounds__(256, 1)
void proj_y(const bf16_t* __restrict__ h,    // [B][512]
            const bf16_t* __restrict__ Wl,   // [64][512] bf16
            const float* __restrict__ bl,    // [64]
            float* __restrict__ y) {         // [B][64] fp32
  __shared__ __align__(16) char smem[4 * 8192];
  const int tid = threadIdx.x;
  const int lane = tid & 63;
  const int w = tid >> 6;
  const int row0 = blockIdx.x * 64;
  const int l3 = lane >> 3;
  const int q8 = ((lane & 7) ^ l3) * 8;

  auto stage = [&](int kc, int buf) {
    char* Ab = smem + buf * 8192;
    char* Bb = smem + 16384 + buf * 8192;
    #pragma unroll
    for (int ii = 0; ii < 2; ++ii) {
      int i = 2 * w + ii;
      int rl = i * 8 + l3;
      llds16(h  + (size_t)(row0 + rl) * N_H + kc * 64 + q8, Ab + i * 1024);
      llds16(Wl + (size_t)rl * N_H + kc * 64 + q8,          Bb + i * 1024);
    }
  };

  f32x4 acc[4];
  #pragma unroll
  for (int ci = 0; ci < 4; ++ci) acc[ci] = (f32x4){0.f, 0.f, 0.f, 0.f};
  const int fr = lane & 15, g4 = lane >> 4, px = lane & 7;

  stage(0, 0);
  for (int kc = 0; kc < 8; ++kc) {
    asm volatile("s_waitcnt vmcnt(0)" ::: "memory");
    __syncthreads();
    if (kc + 1 < 8) stage(kc + 1, (kc + 1) & 1);
    const char* Ab = smem + (kc & 1) * 8192;
    const char* Bb = smem + 16384 + (kc & 1) * 8192;
    #pragma unroll
    for (int kk = 0; kk < 2; ++kk) {
      int p = (kk * 4 + g4) ^ px;
      bf16x8 av = *(const bf16x8*)(Ab + (16 * w + fr) * 128 + p * 16);
      #pragma unroll
      for (int ci = 0; ci < 4; ++ci) {
        bf16x8 bv = *(const bf16x8*)(Bb + (ci * 16 + fr) * 128 + p * 16);
        acc[ci] = __builtin_amdgcn_mfma_f32_16x16x32_bf16(av, bv, acc[ci], 0, 0, 0);
      }
    }
  }
  #pragma unroll
  for (int ci = 0; ci < 4; ++ci) {
    float bb = bl[ci * 16 + fr];
    #pragma unroll
    for (int r = 0; r < 4; ++r) {
      int row = row0 + 16 * w + g4 * 4 + r;
      y[(size_t)row * N_D + ci * 16 + fr] = acc[ci][r] + bb;
    }
  }
}

// ---------------- host ----------------
extern "C" void kernel_launch(void* const* d_in, const int* in_sizes, int n_in,
                              void* d_out, int out_size, void* d_ws, size_t ws_size,
                              hipStream_t stream) {
  (void)in_sizes; (void)n_in; (void)out_size; (void)ws_size;
  const float* x_f  = (const float*)d_in[0];
  const float* eWih = (const float*)d_in[1];
  const float* eWhh = (const float*)d_in[2];
  const float* ebih = (const float*)d_in[3];
  const float* ebhh = (const float*)d_in[4];
  const float* dWih = (const float*)d_in[5];
  const float* dWhh = (const float*)d_in[6];
  const float* dbih = (const float*)d_in[7];
  const float* dbhh = (const float*)d_in[8];
  const float* linW = (const float*)d_in[9];
  const float* linb = (const float*)d_in[10];
  float* out = (float*)d_out;

  char* ws = (char*)d_ws;
  size_t off = 0;
  auto alloc = [&](size_t bytes) {
    char* p = ws + off;
    off += (bytes + 255) & ~(size_t)255;
    return p;
  };
  bf16_t* Wenc  = (bf16_t*)alloc(2048ull * 576 * 2);
  bf16_t* Wdec0 = (bf16_t*)alloc(2048ull * 512 * 2);
  bf16_t* Weff  = (bf16_t*)alloc(2048ull * 512 * 2);
  bf16_t* linWb = (bf16_t*)alloc(64ull * 512 * 2);
  float*  benc  = (float*)alloc(2048 * 4);
  float*  bdec0 = (float*)alloc(2048 * 4);
  float*  beff  = (float*)alloc(2048 * 4);
  bf16_t* xb    = (bf16_t*)alloc((size_t)N_TIN * N_B * N_D * 2);
  bf16_t* h_a   = (bf16_t*)alloc((size_t)N_B * N_H * 2);
  bf16_t* h_b   = (bf16_t*)alloc((size_t)N_B * N_H * 2);
  float*  cbuf  = (float*)alloc((size_t)N_B * N_H * 4);

  prep_enc_w<<<2048, 256, 0, stream>>>(eWih, eWhh, ebih, ebhh, Wenc, benc);
  prep_dec_w<<<2048, 256, 0, stream>>>(dWih, dWhh, dbih, dbhh, linW, linb,
                                       Wdec0, Weff, bdec0, beff);
  cvt_bf16_v4<<<32, 256, 0, stream>>>(linW, linWb, 64 * 512 / 4);
  cvt_bf16_v4<<<2048, 256, 0, stream>>>(x_f, xb, N_TIN * N_B * N_D / 4);
  hipMemsetAsync(h_a, 0, (size_t)N_B * N_H * 2, stream);
  hipMemsetAsync(cbuf, 0, (size_t)N_B * N_H * 4, stream);

  dim3 grid(32, 8);
  // encoder: 336 steps, h ping-pongs a->b->a...; 336 even => final h in h_a
  for (int t = 0; t < N_TIN; ++t) {
    const bf16_t* hi = (t & 1) ? h_b : h_a;
    bf16_t* ho = (t & 1) ? h_a : h_b;
    lstm_step<576, 64><<<grid, 256, 0, stream>>>(xb + (size_t)t * N_B * N_D,
                                                 hi, Wenc, benc, cbuf, ho);
  }
  // decoder: step 0 uses Whh only (x0 == 0); steps >0 use folded W_eff
  for (int t = 0; t < N_TOUT; ++t) {
    const bf16_t* hi = (t & 1) ? h_b : h_a;
    bf16_t* ho = (t & 1) ? h_a : h_b;
    const bf16_t* W  = (t == 0) ? Wdec0 : Weff;
    const float*  bb = (t == 0) ? bdec0 : beff;
    lstm_step<512, 0><<<grid, 256, 0, stream>>>(nullptr, hi, W, bb, cbuf, ho);
    proj_y<<<32, 256, 0, stream>>>(ho, linWb, linb, out + (size_t)t * N_B * N_D);
  }
}